// Round 1
// baseline (318.239 us; speedup 1.0000x reference)
//
#include <hip/hip_runtime.h>

// Problem constants (match reference)
#define N_NODES 8192
#define E_EDGES 262144
#define EPS_F   1e-8f

#define BLK 256
#define NBLK (E_EDGES / BLK)   // 1024 blocks, one edge pair per thread

// Kernel 1: gather pos/neg predictions, compute log terms, per-block reduce.
// partials layout: partials[2*b] = sum(log(pos+eps)) for block b,
//                  partials[2*b+1] = sum(log(1-neg+eps)) for block b.
__global__ __launch_bounds__(BLK) void gather_reduce_kernel(
    const float* __restrict__ adj,
    const int*   __restrict__ edge_index,   // [2][E] row-major: src then dst
    const int*   __restrict__ neg_edges,    // [E][2] row-major: interleaved
    float*       __restrict__ partials)
{
    const int i   = blockIdx.x * BLK + threadIdx.x;
    const int lid = threadIdx.x & 63;
    const int wid = threadIdx.x >> 6;

    // Coalesced index loads
    const int src = edge_index[i];
    const int dst = edge_index[E_EDGES + i];
    const int2 np = ((const int2*)neg_edges)[i];

    // Random gathers (the expensive part) — issue both before using either
    const float pos = adj[(size_t)src * N_NODES + (size_t)dst];
    const float neg = adj[(size_t)np.x * N_NODES + (size_t)np.y];

    float lp = logf(pos + EPS_F);
    float ln = logf(1.0f - neg + EPS_F);

    // Wave-64 reduction
    #pragma unroll
    for (int off = 32; off > 0; off >>= 1) {
        lp += __shfl_down(lp, off, 64);
        ln += __shfl_down(ln, off, 64);
    }

    __shared__ float s_lp[BLK / 64];
    __shared__ float s_ln[BLK / 64];
    if (lid == 0) { s_lp[wid] = lp; s_ln[wid] = ln; }
    __syncthreads();

    if (threadIdx.x == 0) {
        float tlp = 0.f, tln = 0.f;
        #pragma unroll
        for (int w = 0; w < BLK / 64; ++w) { tlp += s_lp[w]; tln += s_ln[w]; }
        partials[2 * blockIdx.x]     = tlp;
        partials[2 * blockIdx.x + 1] = tln;
    }
}

// Kernel 2: reduce the NBLK partial pairs, fold in codebook terms, write scalar.
__global__ __launch_bounds__(1024) void finalize_kernel(
    const float* __restrict__ partials,
    const float* __restrict__ codebook,
    float*       __restrict__ out)
{
    const int t   = threadIdx.x;   // 1024 threads, one partial pair each
    const int lid = t & 63;
    const int wid = t >> 6;

    float lp = partials[2 * t];
    float ln = partials[2 * t + 1];

    #pragma unroll
    for (int off = 32; off > 0; off >>= 1) {
        lp += __shfl_down(lp, off, 64);
        ln += __shfl_down(ln, off, 64);
    }

    __shared__ float s_lp[16];
    __shared__ float s_ln[16];
    if (lid == 0) { s_lp[wid] = lp; s_ln[wid] = ln; }
    __syncthreads();

    if (t == 0) {
        float tlp = 0.f, tln = 0.f;
        #pragma unroll
        for (int w = 0; w < 16; ++w) { tlp += s_lp[w]; tln += s_ln[w]; }
        const float pos_loss = -tlp / (float)E_EDGES;
        const float neg_loss = -tln / (float)E_EDGES;
        const float rec_loss = pos_loss + neg_loss;           // REC_WEIGHT = 1.0
        out[0] = rec_loss + codebook[0] + codebook[1] + codebook[2] + codebook[3];
    }
}

extern "C" void kernel_launch(void* const* d_in, const int* in_sizes, int n_in,
                              void* d_out, int out_size, void* d_ws, size_t ws_size,
                              hipStream_t stream)
{
    const float* adj       = (const float*)d_in[0];
    const float* codebook  = (const float*)d_in[1];
    const int*   edge_idx  = (const int*)d_in[2];
    const int*   neg_edges = (const int*)d_in[3];
    float*       out       = (float*)d_out;
    float*       partials  = (float*)d_ws;   // 2*NBLK floats; fully written each call

    gather_reduce_kernel<<<NBLK, BLK, 0, stream>>>(adj, edge_idx, neg_edges, partials);
    finalize_kernel<<<1, 1024, 0, stream>>>(partials, codebook, out);
}

// Round 2
// 317.782 us; speedup vs baseline: 1.0014x; 1.0014x over previous
//
#include <hip/hip_runtime.h>

// Problem constants (match reference)
#define N_NODES 8192
#define E_EDGES 262144
#define EPS_F   1e-8f

#define BLK      256
#define NBLK_POS (E_EDGES / BLK)     // 1024 blocks for pos edges
#define NBLK     (2 * NBLK_POS)      // + 1024 blocks for neg edges = 2048 total

// Kernel 1: one random gather per thread (max TLP to hide HBM latency).
// Blocks [0, NBLK_POS) handle pos edges; [NBLK_POS, NBLK) handle neg edges.
// partials[b] = block b's sum of log terms (pos half / neg half separately).
__global__ __launch_bounds__(BLK) void gather_reduce_kernel(
    const float* __restrict__ adj,
    const int*   __restrict__ edge_index,   // [2][E]: src row then dst row
    const int*   __restrict__ neg_edges,    // [E][2] interleaved
    float*       __restrict__ partials)
{
    const int b      = blockIdx.x;
    const bool is_pos = (b < NBLK_POS);
    const int i      = (is_pos ? b : b - NBLK_POS) * BLK + threadIdx.x;
    const int lid    = threadIdx.x & 63;
    const int wid    = threadIdx.x >> 6;

    float val;
    if (is_pos) {
        const int src = edge_index[i];
        const int dst = edge_index[E_EDGES + i];
        const float p = adj[(size_t)src * N_NODES + (size_t)dst];
        val = logf(p + EPS_F);
    } else {
        const int2 np = ((const int2*)neg_edges)[i];
        const float p = adj[(size_t)np.x * N_NODES + (size_t)np.y];
        val = logf(1.0f - p + EPS_F);
    }

    // Wave-64 reduction
    #pragma unroll
    for (int off = 32; off > 0; off >>= 1)
        val += __shfl_down(val, off, 64);

    __shared__ float s_v[BLK / 64];
    if (lid == 0) s_v[wid] = val;
    __syncthreads();

    if (threadIdx.x == 0) {
        float t = 0.f;
        #pragma unroll
        for (int w = 0; w < BLK / 64; ++w) t += s_v[w];
        partials[b] = t;
    }
}

// Kernel 2: reduce 2048 partials (pos half + neg half), fold in codebook terms.
__global__ __launch_bounds__(1024) void finalize_kernel(
    const float* __restrict__ partials,
    const float* __restrict__ codebook,
    float*       __restrict__ out)
{
    const int t   = threadIdx.x;   // 1024 threads
    const int lid = t & 63;
    const int wid = t >> 6;

    float lp = partials[t];              // pos-half partial
    float ln = partials[NBLK_POS + t];   // neg-half partial

    #pragma unroll
    for (int off = 32; off > 0; off >>= 1) {
        lp += __shfl_down(lp, off, 64);
        ln += __shfl_down(ln, off, 64);
    }

    __shared__ float s_lp[16];
    __shared__ float s_ln[16];
    if (lid == 0) { s_lp[wid] = lp; s_ln[wid] = ln; }
    __syncthreads();

    if (t == 0) {
        float tlp = 0.f, tln = 0.f;
        #pragma unroll
        for (int w = 0; w < 16; ++w) { tlp += s_lp[w]; tln += s_ln[w]; }
        const float pos_loss = -tlp / (float)E_EDGES;
        const float neg_loss = -tln / (float)E_EDGES;
        const float rec_loss = pos_loss + neg_loss;          // REC_WEIGHT = 1.0
        out[0] = rec_loss + codebook[0] + codebook[1] + codebook[2] + codebook[3];
    }
}

extern "C" void kernel_launch(void* const* d_in, const int* in_sizes, int n_in,
                              void* d_out, int out_size, void* d_ws, size_t ws_size,
                              hipStream_t stream)
{
    const float* adj       = (const float*)d_in[0];
    const float* codebook  = (const float*)d_in[1];
    const int*   edge_idx  = (const int*)d_in[2];
    const int*   neg_edges = (const int*)d_in[3];
    float*       out       = (float*)d_out;
    float*       partials  = (float*)d_ws;   // NBLK floats; fully written each call

    gather_reduce_kernel<<<NBLK, BLK, 0, stream>>>(adj, edge_idx, neg_edges, partials);
    finalize_kernel<<<1, 1024, 0, stream>>>(partials, codebook, out);
}